// Round 10
// baseline (282.503 us; speedup 1.0000x reference)
//
#include <hip/hip_runtime.h>
#include <stdint.h>

// ---------------------------------------------------------------------------
// RoIHead: out = crop_and_resize(feature, rois) @ (W_fc @ [W_loc|W_score])
//                + (b_fc @ [W_loc|W_score] + [b_loc|b_score])
// R10: granularity rewrite of gemm1 per R9's counter row (Occ 21%, VALU 21%,
// MFMA 4.4%, HBM 1.24 TB/s: latency-bound with a bad address stream).
// R2-R9 read A as 256B-per-16KB-stride chunks over ~45K streams -> DRAM
// near-random 256B (~2.6 TB/s). Now each A-load instr = 1 KB contiguous
// (lane i = bytes 16i..16i+15 of ONE row). Full-K blocks (392, all resident
// at 2/CU), B kept in registers from L2 (4-deep), A reg->cvt->LDS dbuf,
// ONE barrier per 256-col super-phase, zero manual vmcnt.
// ---------------------------------------------------------------------------

typedef float          f32x4 __attribute__((ext_vector_type(4)));
typedef __bf16         bfx8  __attribute__((ext_vector_type(8)));
typedef __bf16         bfx4  __attribute__((ext_vector_type(4)));
typedef __bf16         bfx2  __attribute__((ext_vector_type(2)));

#define KBIG 25088   // 7*7*512
#define NMID 4096    // FC_OUT
#define NROIS 2000
#define G1BLOCKS 392 // 25088/64, full K per block
#define SPLITS 28    // gemm2 K-splits

__device__ __forceinline__ void gll16(const void* g, void* l) {
  __builtin_amdgcn_global_load_lds(
      (const __attribute__((address_space(1))) void*)(uintptr_t)(g),
      (__attribute__((address_space(3))) void*)(uintptr_t)(l), 16, 0, 0);
}

// ---------------------------------------------------------------------------
// prep: blocks 0..2047 build WcatT[128][4096] bf16; 2048..2175 compute bc.
// ---------------------------------------------------------------------------
__global__ __launch_bounds__(256) void k_prep(const float* __restrict__ Wl,
                                              const float* __restrict__ Ws,
                                              const float* __restrict__ bfc,
                                              const float* __restrict__ bl,
                                              const float* __restrict__ bs,
                                              unsigned short* __restrict__ WcatT,
                                              float* __restrict__ bc) {
  if (blockIdx.x < 2048) {
    int idx = blockIdx.x * 256 + threadIdx.x;
    int c = idx >> 12, k = idx & 4095;
    float v = 0.0f;
    if (c < 84)       v = Wl[k * 84 + c];
    else if (c < 105) v = Ws[k * 21 + (c - 84)];
    ((__bf16*)WcatT)[idx] = (__bf16)v;
  } else {
    int c = blockIdx.x - 2048;   // 0..127
    int t = threadIdx.x;
    __shared__ float red[256];
    float p = 0.0f;
    if (c < 105) {
      for (int k = t; k < 4096; k += 256) {
        float w = (c < 84) ? Wl[k * 84 + c] : Ws[k * 21 + (c - 84)];
        p += bfc[k] * w;
      }
    }
    red[t] = p;
    __syncthreads();
    for (int s = 128; s > 0; s >>= 1) {
      if (t < s) red[t] += red[t + s];
      __syncthreads();
    }
    if (t == 0) {
      float bias = (c < 84) ? bl[c] : (c < 105 ? bs[c - 84] : 0.0f);
      bc[c] = (c < 105) ? (red[0] + bias) : 0.0f;
    }
  }
}

// ---------------------------------------------------------------------------
// Fused: blocks [0,392) = GEMM1 (BM=64, K=4096), [392,2392) = pool.
// GEMM1 -> WcT[n][m] bf16 directly (no partials).
//   16 super-phases (SP) of 256 cols. Per SP per wave: 16 rows x 1 instr of
//   1 KB dense (lane*16B within one row) -> reg -> cvt -> swizzled ds_write
//   into sA[2][64 rows][512B]. B-frags straight from L2 into bq[4][4]
//   (4-phase software pipeline, reg-dep waits). 8 MFMA k-steps per SP.
//   Sync: ONE {lgkmcnt(0); s_barrier; sched_barrier} per SP.
// ---------------------------------------------------------------------------
__global__ __launch_bounds__(256, 2) void k_pool_gemm1(
    const float* __restrict__ F, const float* __restrict__ rois,
    const int* __restrict__ ihp, const int* __restrict__ iwp,
    unsigned short* __restrict__ A,
    const float* __restrict__ Wfc, const unsigned short* __restrict__ WcatTu,
    unsigned short* __restrict__ WcTu) {
  const int t = threadIdx.x;
  __shared__ __align__(16) char sA[65536];   // [2][64 rows][512 B bf16]
  if (blockIdx.x < G1BLOCKS) {
    // ---------------- GEMM1 ----------------
    const int lane = t & 63, wid = t >> 6;
    const int wm = wid >> 1, wn = wid & 1;
    const int l15 = lane & 15, l4 = lane >> 4;
    const int m0 = blockIdx.x * 64;
    const __bf16* Wcat = (const __bf16*)WcatTu;
    f32x4 acc[2][4] = {};
    f32x4 rA[16];          // next-SP A: 16 rows x 16B/lane (1KB dense instrs)
    bfx8 bq[4][4];         // B-frag pipeline, 4 phases deep

    auto bload = [&](bfx8* dst, int k) {
#pragma unroll
      for (int ni = 0; ni < 4; ++ni)
        dst[ni] = *(const bfx8*)(Wcat + (size_t)(wn * 64 + ni * 16 + l15) * NMID + k + l4 * 8);
    };
    auto aload = [&](f32x4* d, int spn, int jb) {
      const float* src = Wfc + (size_t)(m0 + wid * 16 + jb) * NMID + spn * 256 + lane * 4;
#pragma unroll
      for (int j = 0; j < 8; ++j)
        d[j] = *(const f32x4*)(src + (size_t)j * NMID);
    };
    auto aput = [&](const f32x4* d, int buf, int jb) {
#pragma unroll
      for (int j = 0; j < 8; ++j) {
        const int r = wid * 16 + jb + j;
        bfx4 p;
#pragma unroll
        for (int jj = 0; jj < 4; ++jj) p[jj] = (__bf16)d[j][jj];
        *(bfx4*)(sA + buf * 32768 + r * 512 +
                 ((((lane >> 1) ^ (r & 15)) << 4)) + (lane & 1) * 8) = p;
      }
    };
    auto domfma = [&](int buf, int kk, bfx8* bqp) {
#pragma unroll
      for (int mi = 0; mi < 2; ++mi) {
        const int R = wm * 32 + mi * 16 + l15;
        const int c16 = kk * 4 + l4;
        bfx8 af = *(const bfx8*)(sA + buf * 32768 + R * 512 + ((c16 ^ (R & 15)) << 4));
#pragma unroll
        for (int ni = 0; ni < 4; ++ni)
          acc[mi][ni] = __builtin_amdgcn_mfma_f32_16x16x32_bf16(af, bqp[ni], acc[mi][ni], 0, 0, 0);
      }
    };

    // prologue: B phases 0..3; SP0 staged into buf0
    bload(bq[0], 0); bload(bq[1], 32); bload(bq[2], 64); bload(bq[3], 96);
    aload(rA, 0, 0);
    aload(rA + 8, 0, 8);
    aput(rA, 0, 0);
    aput(rA + 8, 0, 8);
    asm volatile("s_waitcnt lgkmcnt(0)" ::: "memory");
    __builtin_amdgcn_s_barrier();
    __builtin_amdgcn_sched_barrier(0);

    for (int sp = 0; sp < 15; ++sp) {
      const int buf = sp & 1;
#pragma unroll
      for (int kk = 0; kk < 8; ++kk) {
        domfma(buf, kk, bq[kk & 3]);
        bload(bq[kk & 3], sp * 256 + kk * 32 + 128);   // phase p+4
        if (kk == 0) aload(rA, sp + 1, 0);             // next SP, dense 1KB x8
        if (kk == 1) aload(rA + 8, sp + 1, 8);
        if (kk == 6) aput(rA, buf ^ 1, 0);
        if (kk == 7) aput(rA + 8, buf ^ 1, 8);
      }
      asm volatile("s_waitcnt lgkmcnt(0)" ::: "memory");
      __builtin_amdgcn_s_barrier();
      __builtin_amdgcn_sched_barrier(0);
    }
    // sp = 15 (buf 1), no staging; B issues only while p+4 <= 127
#pragma unroll
    for (int kk = 0; kk < 8; ++kk) {
      domfma(1, kk, bq[kk & 3]);
      if (kk < 4) bload(bq[kk & 3], 15 * 256 + kk * 32 + 128);
    }
    // epilogue: WcT[n][m] bf16; D col(l15)=n-frag, row(l4*4+i)=m
#pragma unroll
    for (int mi = 0; mi < 2; ++mi)
#pragma unroll
      for (int ni = 0; ni < 4; ++ni) {
        const int n = wn * 64 + ni * 16 + l15;
        const int m = m0 + wm * 32 + mi * 16 + l4 * 4;
        bfx4 pk;
#pragma unroll
        for (int i = 0; i < 4; ++i) pk[i] = (__bf16)acc[mi][ni][i];
        *(bfx4*)((__bf16*)WcTu + (size_t)n * KBIG + m) = pk;
      }
  } else {
    // ---------------- pool (next-cell prefetch) ----------------
    const int r = blockIdx.x - G1BLOCKS;
    const float ih = (float)ihp[0], iw = (float)iwp[0];
    const float y1 = rois[r * 4 + 0] / ih;
    const float x1 = rois[r * 4 + 1] / iw;
    const float y2 = rois[r * 4 + 2] / ih;
    const float x2 = rois[r * 4 + 3] / iw;
    const float sy = (y2 - y1) * 49.0f / 6.0f;
    const float sx = (x2 - x1) * 49.0f / 6.0f;
    const int ch = t * 2;
    __bf16* __restrict__ Arow = (__bf16*)(A + (size_t)r * KBIG);

    auto cellcoords = [&](int cell, int& o00, int& o01, int& o10, int& o11,
                          float& yl, float& xl, bool& valid) {
      const int iy = cell / 7, ix = cell - iy * 7;
      const float in_y = y1 * 49.0f + (float)iy * sy;
      const float in_x = x1 * 49.0f + (float)ix * sx;
      const float y0f = floorf(in_y), x0f = floorf(in_x);
      yl = in_y - y0f; xl = in_x - x0f;
      const int y0  = (int)fminf(fmaxf(y0f, 0.0f), 49.0f);
      const int y1i = (int)fminf(fmaxf(y0f + 1.0f, 0.0f), 49.0f);
      const int x0  = (int)fminf(fmaxf(x0f, 0.0f), 49.0f);
      const int x1i = (int)fminf(fmaxf(x0f + 1.0f, 0.0f), 49.0f);
      valid = (in_y >= 0.0f) && (in_y <= 49.0f) && (in_x >= 0.0f) && (in_x <= 49.0f);
      o00 = (y0 * 50 + x0) * 512;  o01 = (y0 * 50 + x1i) * 512;
      o10 = (y1i * 50 + x0) * 512; o11 = (y1i * 50 + x1i) * 512;
    };

    int o00, o01, o10, o11; float yl, xl; bool valid;
    cellcoords(0, o00, o01, o10, o11, yl, xl, valid);
    float2 f00 = *(const float2*)&F[o00 + ch];
    float2 f01 = *(const float2*)&F[o01 + ch];
    float2 f10 = *(const float2*)&F[o10 + ch];
    float2 f11 = *(const float2*)&F[o11 + ch];

    for (int cell = 0; cell < 49; ++cell) {
      const float2 g00 = f00, g01 = f01, g10 = f10, g11 = f11;
      const float pyl = yl, pxl = xl;
      const bool pv = valid;
      if (cell < 48) {
        cellcoords(cell + 1, o00, o01, o10, o11, yl, xl, valid);
        f00 = *(const float2*)&F[o00 + ch];
        f01 = *(const float2*)&F[o01 + ch];
        f10 = *(const float2*)&F[o10 + ch];
        f11 = *(const float2*)&F[o11 + ch];
      }
      float oA = 0.0f, oB = 0.0f;
      if (pv) {
        float t0 = g00.x * (1.0f - pxl) + g01.x * pxl;
        float t1 = g00.y * (1.0f - pxl) + g01.y * pxl;
        float b0 = g10.x * (1.0f - pxl) + g11.x * pxl;
        float b1 = g10.y * (1.0f - pxl) + g11.y * pxl;
        oA = t0 * (1.0f - pyl) + b0 * pyl;
        oB = t1 * (1.0f - pyl) + b1 * pyl;
      }
      bfx2 v; v[0] = (__bf16)oA; v[1] = (__bf16)oB;
      *(bfx2*)(Arow + cell * 512 + ch) = v;
    }
  }
}

// ---------------------------------------------------------------------------
// GEMM2: P[mt*28+sp][64][128] f32 = pool_tile(mt) @ WcT_slice(sp). (proven)
// ---------------------------------------------------------------------------
__global__ __launch_bounds__(256) void k_gemm2(const unsigned short* __restrict__ Ap,
                                               const unsigned short* __restrict__ WcT,
                                               float* __restrict__ P) {
  __shared__ __align__(16) char S[49152];
  const int t = threadIdx.x;
  const int lane = t & 63, wid = t >> 6;
  const int wm = wid >> 1, wn = wid & 1;
  const int l15 = lane & 15, l4 = lane >> 4;
  const int mt = blockIdx.x, sp = blockIdx.y;
  const int kbase = sp * 896;     // 14 BK-steps of 64
  const int jlog = (t & 7) ^ ((t >> 3) & 7);
  f32x4 acc[2][4] = {};

  int ar0 = mt * 64 + (t >> 3);
  int ar1 = ar0 + 32;
  if (ar0 > NROIS - 1) ar0 = NROIS - 1;
  if (ar1 > NROIS - 1) ar1 = NROIS - 1;
  const unsigned short* asrc0 = Ap + (size_t)ar0 * KBIG + jlog * 8;
  const unsigned short* asrc1 = Ap + (size_t)ar1 * KBIG + jlog * 8;

  auto stage2 = [&](int c, int off) {
    const int k0 = kbase + c * 64;
    gll16(asrc0 + k0, S + off + wid * 1024);
    gll16(asrc1 + k0, S + off + 4096 + wid * 1024);
#pragma unroll
    for (int q = 0; q < 4; ++q)
      gll16(WcT + (size_t)(q * 32 + (t >> 3)) * KBIG + k0 + jlog * 8,
            S + off + 8192 + q * 4096 + wid * 1024);
  };
  auto compute2 = [&](int off) {
#pragma unroll
    for (int kh = 0; kh < 2; ++kh) {
      bfx8 af[2], bfr[4];
#pragma unroll
      for (int mi = 0; mi < 2; ++mi) {
        const int row = wm * 32 + mi * 16 + l15;
        af[mi] = *(const bfx8*)(S + off + row * 128 + ((((kh << 2) + l4) ^ (row & 7)) << 4));
      }
#pragma unroll
      for (int ni = 0; ni < 4; ++ni) {
        const int row = wn * 64 + ni * 16 + l15;
        bfr[ni] = *(const bfx8*)(S + off + 8192 + row * 128 + ((((kh << 2) + l4) ^ (row & 7)) << 4));
      }
#pragma unroll
      for (int mi = 0; mi < 2; ++mi)
#pragma unroll
        for (int ni = 0; ni < 4; ++ni)
          acc[mi][ni] = __builtin_amdgcn_mfma_f32_16x16x32_bf16(af[mi], bfr[ni], acc[mi][ni], 0, 0, 0);
    }
  };

  stage2(0, 0);
  for (int cc = 0; cc < 7; ++cc) {
    const int c0 = cc * 2;
    stage2(c0 + 1, 24576);
    asm volatile("s_waitcnt vmcnt(6)" ::: "memory");
    __builtin_amdgcn_s_barrier();
    __builtin_amdgcn_sched_barrier(0);
    compute2(0);
    __builtin_amdgcn_s_barrier();
    stage2((c0 + 2 < 14) ? c0 + 2 : 13, 0);
    asm volatile("s_waitcnt vmcnt(6)" ::: "memory");
    __builtin_amdgcn_s_barrier();
    __builtin_amdgcn_sched_barrier(0);
    compute2(24576);
    __builtin_amdgcn_s_barrier();
  }
  asm volatile("s_waitcnt vmcnt(0)" ::: "memory");
  float* out = P + (size_t)(mt * SPLITS + sp) * 8192;
#pragma unroll
  for (int mi = 0; mi < 2; ++mi)
#pragma unroll
    for (int ni = 0; ni < 4; ++ni)
#pragma unroll
      for (int i = 0; i < 4; ++i)
        out[(wm * 32 + mi * 16 + l4 * 4 + i) * 128 + wn * 64 + ni * 16 + l15] = acc[mi][ni][i];
}

// ---------------------------------------------------------------------------
// reduce: sum 28 K-split partials + bias, scatter into the two outputs.
// ---------------------------------------------------------------------------
__global__ __launch_bounds__(128) void k_reduce(const float* __restrict__ P,
                                                const float* __restrict__ bc,
                                                float* __restrict__ out) {
  const int m = blockIdx.x;     // 0..1999
  const int c = threadIdx.x;    // 0..127
  if (c >= 105) return;
  const int mt = m >> 6, r = m & 63;
  float sum = 0.0f;
#pragma unroll
  for (int s = 0; s < SPLITS; ++s)
    sum += P[(size_t)(mt * SPLITS + s) * 8192 + r * 128 + c];
  sum += bc[c];
  if (c < 84) out[m * 84 + c] = sum;
  else        out[168000 + m * 21 + (c - 84)] = sum;
}

// ---------------------------------------------------------------------------
extern "C" void kernel_launch(void* const* d_in, const int* in_sizes, int n_in,
                              void* d_out, int out_size, void* d_ws, size_t ws_size,
                              hipStream_t stream) {
  const float* F    = (const float*)d_in[0];
  const float* rois = (const float*)d_in[1];
  const int*   ih   = (const int*)d_in[2];
  const int*   iw   = (const int*)d_in[3];
  const float* Wfc  = (const float*)d_in[4];
  const float* bfc  = (const float*)d_in[5];
  const float* Wl   = (const float*)d_in[6];
  const float* bl   = (const float*)d_in[7];
  const float* Ws   = (const float*)d_in[8];
  const float* bs   = (const float*)d_in[9];
  (void)in_sizes; (void)n_in; (void)out_size; (void)ws_size;

  char* ws = (char*)d_ws;
  // ws layout (bytes):
  //   pool  bf16 [2000][25088]      @ 0          (100,352,000)
  //   WcatT bf16 [128][4096]        @ 100352000  (1,048,576)
  //   WcT   bf16 [128][25088]       @ 101400576  (6,422,528)
  //   bc    f32  [128]              @ 107823104  (512)
  //   P     f32  [896][64][128]     @ 107823616  (29,360,128)  total ~137 MB
  unsigned short* Apool = (unsigned short*)(ws);
  unsigned short* WcatT = (unsigned short*)(ws + 100352000);
  unsigned short* WcT   = (unsigned short*)(ws + 101400576);
  float*          bc    = (float*)(ws + 107823104);
  float*          P     = (float*)(ws + 107823616);
  float*          out   = (float*)d_out;

  k_prep      <<<2176, 256, 0, stream>>>(Wl, Ws, bfc, bl, bs, WcatT, bc);
  k_pool_gemm1<<<G1BLOCKS + NROIS, 256, 0, stream>>>(F, rois, ih, iw, Apool,
                                                     Wfc, WcatT, WcT);
  k_gemm2     <<<dim3(32, SPLITS), 256, 0, stream>>>(Apool, WcT, P);
  k_reduce    <<<NROIS, 128, 0, stream>>>(P, bc, out);
}